// Round 1
// baseline (632.637 us; speedup 1.0000x reference)
//
#include <hip/hip_runtime.h>
#include <stdint.h>

// Shapes fixed by the problem: B=4,H=16 -> BH=64; S=1024; D=64.
// d_ws layout (needs 28 MB):
//   [0,8M)    Qb  bf16 [bh][s][d]  (pre-scaled by 1/8)
//   [8M,16M)  Kb  bf16 [bh][s][d]
//   [16M,24M) Vt  bf16 [bh][d][s]  (V transposed)
//   [24M,28M) Mb  u8   [b][q][k]   (mask canonicalized to bytes)

#define S_LEN 1024
#define D_DIM 64
#define QT 16
#define NEG_FILL (-1000000000.0f)
#define LOG2E 1.44269504088896340736f

typedef __bf16 bf16x8 __attribute__((ext_vector_type(8)));
typedef float f32x4 __attribute__((ext_vector_type(4)));
typedef unsigned short u16x4 __attribute__((ext_vector_type(4)));
typedef unsigned short u16x8 __attribute__((ext_vector_type(8)));

__device__ __forceinline__ unsigned short f2bf(float x) {
    unsigned u = __builtin_bit_cast(unsigned, x);
    u += 0x7fffu + ((u >> 16) & 1u);
    return (unsigned short)(u >> 16);
}
__device__ __forceinline__ float bf2f(unsigned short b) {
    return __builtin_bit_cast(float, (unsigned)b << 16);
}

// ---- prep: q,k -> bf16 (q pre-scaled by 1/TEMPERATURE) -------------------
__global__ void prep_qk(const float* __restrict__ q, const float* __restrict__ k,
                        unsigned short* __restrict__ Qb, unsigned short* __restrict__ Kb)
{
    int i = blockIdx.x * 256 + threadIdx.x;       // float4 index, 1,048,576 total
    f32x4 q4 = ((const f32x4*)q)[i];
    f32x4 k4 = ((const f32x4*)k)[i];
    u16x4 qo, ko;
#pragma unroll
    for (int j = 0; j < 4; ++j) {
        qo[j] = f2bf(q4[j] * 0.125f);
        ko[j] = f2bf(k4[j]);
    }
    ((u16x4*)Qb)[i] = qo;
    ((u16x4*)Kb)[i] = ko;
}

// ---- prep: V -> V^T bf16 (64x64 tiles through LDS) -----------------------
__global__ void prep_vt(const float* __restrict__ v, unsigned short* __restrict__ Vt)
{
    __shared__ unsigned short sT[64 * 72];
    const int bh = blockIdx.x >> 4;
    const int st = blockIdx.x & 15;
    const int t = threadIdx.x;
    const float* vb = v + (size_t)(bh * S_LEN + st * 64) * D_DIM;
#pragma unroll
    for (int p = 0; p < 4; ++p) {
        int lin = p * 256 + t;
        int r = lin >> 4;          // row in s-tile (64 rows)
        int c = lin & 15;          // float4 within row (16 per row)
        f32x4 x = ((const f32x4*)(vb + r * D_DIM))[c];
        unsigned short* dst = &sT[r * 72 + c * 4];
#pragma unroll
        for (int j = 0; j < 4; ++j) dst[j] = f2bf(x[j]);
    }
    __syncthreads();
    unsigned short* ob = Vt + (size_t)bh * D_DIM * S_LEN + st * 64;
#pragma unroll
    for (int p = 0; p < 4; ++p) {
        int lin = p * 256 + t;
        int d = lin >> 4;
        int s4 = (lin & 15) * 4;
        u16x4 o;
#pragma unroll
        for (int j = 0; j < 4; ++j) o[j] = sT[(s4 + j) * 72 + d];
        *(u16x4*)&ob[d * S_LEN + s4] = o;
    }
}

// ---- prep: mask -> bytes, with on-device dtype detection -----------------
// Encodings seen in the wild: bool8 (1B), int32 (4B), fp32 (4B). Scan the
// first 1024 words (safe: 4 KB <= every candidate buffer size) and classify.
__global__ void prep_mask(const void* __restrict__ mraw, unsigned char* __restrict__ Mb)
{
    __shared__ int s_not_int, s_not_f32;
    const int t = threadIdx.x;
    if (t == 0) { s_not_int = 0; s_not_f32 = 0; }
    __syncthreads();
    const unsigned* w = (const unsigned*)mraw;
    int ni = 0, nf = 0;
    for (int j = t; j < 1024; j += 256) {
        unsigned x = w[j];
        if (x > 1u) ni = 1;
        if (x != 0u && x != 0x3f800000u) nf = 1;
    }
    if (ni) s_not_int = 1;
    if (nf) s_not_f32 = 1;
    __syncthreads();
    const int fmt = (s_not_int == 0) ? 0 : ((s_not_f32 == 0) ? 1 : 2);
    const int i = blockIdx.x * 256 + t;           // group of 4 elements
    uchar4 o;
    if (fmt == 0) {        // int32 0/1
        int4 x = ((const int4*)mraw)[i];
        o.x = x.x ? 1 : 0; o.y = x.y ? 1 : 0; o.z = x.z ? 1 : 0; o.w = x.w ? 1 : 0;
    } else if (fmt == 1) { // fp32 0.0/1.0
        float4 x = ((const float4*)mraw)[i];
        o.x = (x.x != 0.f) ? 1 : 0; o.y = (x.y != 0.f) ? 1 : 0;
        o.z = (x.z != 0.f) ? 1 : 0; o.w = (x.w != 0.f) ? 1 : 0;
    } else {               // bool bytes
        uchar4 x = ((const uchar4*)mraw)[i];
        o.x = x.x ? 1 : 0; o.y = x.y ? 1 : 0; o.z = x.z ? 1 : 0; o.w = x.w ? 1 : 0;
    }
    ((uchar4*)Mb)[i] = o;
}

// ---- main: scores -> softmax -> attn write + PV --------------------------
// 1 wg (4 waves) per (bh, 16-row q tile). Scores row fits in LDS -> exact
// (non-online) softmax. LDS rows padded (+8 bf16) so MFMA b128 fragment
// reads are 2-way (free) instead of 16-way bank conflicted.
__global__ __launch_bounds__(256, 3)
void attn_main(const float* __restrict__ simg_, const unsigned short* __restrict__ Qb,
               const unsigned short* __restrict__ Kb, const unsigned short* __restrict__ Vtb,
               const unsigned char* __restrict__ Mb, float* __restrict__ out,
               float* __restrict__ attn)
{
    __shared__ __align__(16) unsigned short sQ[QT * 72];
    __shared__ __align__(16) unsigned short sKV[64 * 72];
    __shared__ __align__(16) unsigned short sS[QT * (S_LEN + 8)];

    const int blk = blockIdx.x;
    const int bh = blk >> 6;
    const int qt = blk & 63;
    const int b = bh >> 4;
    const int t = threadIdx.x;
    const int w = t >> 6;
    const int lane = t & 63;
    const int quad = lane >> 4;
    const int l15 = lane & 15;

    const unsigned short* Qg = Qb + (size_t)(bh * S_LEN + qt * QT) * D_DIM;
    const unsigned short* Kg = Kb + (size_t)bh * S_LEN * D_DIM;
    const unsigned short* Vg = Vtb + (size_t)bh * D_DIM * S_LEN;
    const float* simg = simg_ + ((size_t)(bh * S_LEN + qt * QT)) * S_LEN;
    const unsigned char* mg = Mb + ((size_t)(b * S_LEN + qt * QT)) * S_LEN;
    float* attng = attn + ((size_t)(bh * S_LEN + qt * QT)) * S_LEN;

    // stage Q tile: 16 rows x 8 chunks of 16B
    if (t < 128) {
        int r = t >> 3, c = t & 7;
        *(u16x8*)&sQ[r * 72 + c * 8] = *(const u16x8*)&Qg[r * D_DIM + c * 8];
    }

    // ---- phase 1: scores = (q/8)@k^T, mask, +similarity, park bf16 in LDS
    const int n0 = w * 16;
    for (int kt = 0; kt < 16; ++kt) {
        __syncthreads();
#pragma unroll
        for (int c = 0; c < 2; ++c) {
            int lin = c * 256 + t;
            int r = lin >> 3, ch = lin & 7;
            *(u16x8*)&sKV[r * 72 + ch * 8] =
                *(const u16x8*)&Kg[(size_t)(kt * 64 + r) * D_DIM + ch * 8];
        }
        __syncthreads();
        f32x4 acc = {0.f, 0.f, 0.f, 0.f};
#pragma unroll
        for (int kk = 0; kk < 2; ++kk) {
            bf16x8 av = *(const bf16x8*)&sQ[l15 * 72 + kk * 32 + quad * 8];
            bf16x8 bv = *(const bf16x8*)&sKV[(n0 + l15) * 72 + kk * 32 + quad * 8];
            acc = __builtin_amdgcn_mfma_f32_16x16x32_bf16(av, bv, acc, 0, 0, 0);
        }
        const int colg = kt * 64 + n0 + l15;
#pragma unroll
        for (int r = 0; r < 4; ++r) {
            int row = quad * 4 + r;
            float s = acc[r];
            float sv = simg[row * S_LEN + colg];
            unsigned char mk = mg[row * S_LEN + colg];
            s = (mk ? NEG_FILL : s) + sv;
            sS[row * (S_LEN + 8) + colg] = f2bf(s);
        }
    }
    __syncthreads();

    // ---- phase 2: exact softmax per row (wave w owns rows 4w..4w+3),
    //      write attn fp32 coalesced, rewrite probs as bf16 into sS
#pragma unroll 1
    for (int rr = 0; rr < 4; ++rr) {
        const int row = w * 4 + rr;
        float vals[16];
        float mx = -3.0e38f;
#pragma unroll
        for (int j = 0; j < 4; ++j) {
            int col = j * 256 + lane * 4;
            u16x4 x = *(const u16x4*)&sS[row * (S_LEN + 8) + col];
#pragma unroll
            for (int i = 0; i < 4; ++i) {
                float f = bf2f(x[i]);
                vals[j * 4 + i] = f;
                mx = fmaxf(mx, f);
            }
        }
#pragma unroll
        for (int off = 32; off > 0; off >>= 1)
            mx = fmaxf(mx, __shfl_xor(mx, off, 64));
        float sum = 0.f;
#pragma unroll
        for (int i = 0; i < 16; ++i) {
            float e = exp2f((vals[i] - mx) * LOG2E);  // masked: exp2(-1.4e9)=0 exactly
            vals[i] = e;
            sum += e;
        }
#pragma unroll
        for (int off = 32; off > 0; off >>= 1)
            sum += __shfl_xor(sum, off, 64);
        const float rinv = 1.0f / sum;
#pragma unroll
        for (int j = 0; j < 4; ++j) {
            int col = j * 256 + lane * 4;
            f32x4 p;
            u16x4 pb;
#pragma unroll
            for (int i = 0; i < 4; ++i) {
                float pi = vals[j * 4 + i] * rinv;
                p[i] = pi;
                pb[i] = f2bf(pi);
            }
            *(f32x4*)&attng[row * S_LEN + col] = p;         // 1 KB/wave coalesced
            *(u16x4*)&sS[row * (S_LEN + 8) + col] = pb;
        }
    }

    // ---- phase 3: out = P @ V  (B operand = V^T rows, d = n-index)
    f32x4 oacc = {0.f, 0.f, 0.f, 0.f};
    const int d0 = w * 16;
    for (int kt = 0; kt < 16; ++kt) {
        __syncthreads();
#pragma unroll
        for (int c = 0; c < 2; ++c) {
            int lin = c * 256 + t;
            int r = lin >> 3, ch = lin & 7;
            *(u16x8*)&sKV[r * 72 + ch * 8] =
                *(const u16x8*)&Vg[(size_t)r * S_LEN + kt * 64 + ch * 8];
        }
        __syncthreads();
#pragma unroll
        for (int kk = 0; kk < 2; ++kk) {
            bf16x8 av = *(const bf16x8*)&sS[l15 * (S_LEN + 8) + kt * 64 + kk * 32 + quad * 8];
            bf16x8 bv = *(const bf16x8*)&sKV[(d0 + l15) * 72 + kk * 32 + quad * 8];
            oacc = __builtin_amdgcn_mfma_f32_16x16x32_bf16(av, bv, oacc, 0, 0, 0);
        }
    }
    float* og = out + ((size_t)(bh * S_LEN + qt * QT)) * D_DIM;
#pragma unroll
    for (int r = 0; r < 4; ++r) {
        int row = quad * 4 + r;
        og[row * D_DIM + d0 + l15] = oacc[r];
    }
}

extern "C" void kernel_launch(void* const* d_in, const int* in_sizes, int n_in,
                              void* d_out, int out_size, void* d_ws, size_t ws_size,
                              hipStream_t stream)
{
    const float* q = (const float*)d_in[0];
    const float* k = (const float*)d_in[1];
    const float* v = (const float*)d_in[2];
    const float* sim = (const float*)d_in[3];
    const void* mask = d_in[4];
    float* out = (float*)d_out;
    float* attn = out + (size_t)4 * 16 * 1024 * 64;   // output first, then attn

    char* ws = (char*)d_ws;                           // needs 28 MB
    unsigned short* Qb = (unsigned short*)(ws + (size_t)0);
    unsigned short* Kb = (unsigned short*)(ws + ((size_t)8 << 20));
    unsigned short* Vt = (unsigned short*)(ws + ((size_t)16 << 20));
    unsigned char*  Mb = (unsigned char*)(ws + ((size_t)24 << 20));

    prep_qk<<<4096, 256, 0, stream>>>(q, k, Qb, Kb);
    prep_vt<<<1024, 256, 0, stream>>>(v, Vt);
    prep_mask<<<4096, 256, 0, stream>>>(mask, Mb);
    attn_main<<<4096, 256, 0, stream>>>(sim, Qb, Kb, Vt, Mb, out, attn);
}

// Round 2
// 575.848 us; speedup vs baseline: 1.0986x; 1.0986x over previous
//
#include <hip/hip_runtime.h>
#include <stdint.h>

// Shapes fixed by the problem: B=4,H=16 -> BH=64; S=1024; D=64.
// d_ws layout (needs 28 MB):
//   [0,8M)    Qb  bf16 [bh][s][d]  (pre-scaled by 1/8)
//   [8M,16M)  Kb  bf16 [bh][s][d]
//   [16M,24M) Vt  bf16 [bh][d][s]  (V transposed)
//   [24M,28M) Mb  u8   [b][q][k]   (mask canonicalized to bytes)

#define S_LEN 1024
#define D_DIM 64
#define QT 16
#define SSTR 1032            // sS row stride in u16 (pad 8 -> +4 banks/row)
#define NEG_FILL (-1000000000.0f)
#define LOG2E 1.44269504088896340736f

typedef __bf16 bf16x8 __attribute__((ext_vector_type(8)));
typedef float f32x4 __attribute__((ext_vector_type(4)));
typedef unsigned short u16x4 __attribute__((ext_vector_type(4)));
typedef unsigned short u16x8 __attribute__((ext_vector_type(8)));

__device__ __forceinline__ unsigned short f2bf(float x) {
    unsigned u = __builtin_bit_cast(unsigned, x);
    u += 0x7fffu + ((u >> 16) & 1u);
    return (unsigned short)(u >> 16);
}
__device__ __forceinline__ float bf2f(unsigned short b) {
    return __builtin_bit_cast(float, (unsigned)b << 16);
}

// ---- prep: q,k -> bf16 (q pre-scaled) + mask -> bytes, fused -------------
// Mask dtype detected on-device (bool8 vs int32 vs fp32) by scanning the
// first 1024 words: packed bool bytes give words not in {0,1,0x3f800000}.
__global__ void prep_qkm(const float* __restrict__ q, const float* __restrict__ k,
                         const void* __restrict__ mraw,
                         unsigned short* __restrict__ Qb, unsigned short* __restrict__ Kb,
                         unsigned char* __restrict__ Mb)
{
    const int t = threadIdx.x;
    const int i = blockIdx.x * 256 + t;           // float4 / uchar4 index, 1,048,576 total
    f32x4 q4 = ((const f32x4*)q)[i];
    f32x4 k4 = ((const f32x4*)k)[i];
    u16x4 qo, ko;
#pragma unroll
    for (int j = 0; j < 4; ++j) {
        qo[j] = f2bf(q4[j] * 0.125f);
        ko[j] = f2bf(k4[j]);
    }
    ((u16x4*)Qb)[i] = qo;
    ((u16x4*)Kb)[i] = ko;

    // mask format detect (cheap, L2-broadcast) then canonicalize 4 elements
    __shared__ int s_not_int, s_not_f32;
    if (t == 0) { s_not_int = 0; s_not_f32 = 0; }
    __syncthreads();
    const unsigned* wdd = (const unsigned*)mraw;
    int ni = 0, nf = 0;
    for (int j = t; j < 1024; j += 256) {
        unsigned x = wdd[j];
        if (x > 1u) ni = 1;
        if (x != 0u && x != 0x3f800000u) nf = 1;
    }
    if (ni) s_not_int = 1;
    if (nf) s_not_f32 = 1;
    __syncthreads();
    const int fmt = (s_not_int == 0) ? 0 : ((s_not_f32 == 0) ? 1 : 2);
    uchar4 o;
    if (fmt == 0) {        // int32 0/1
        int4 x = ((const int4*)mraw)[i];
        o.x = x.x ? 1 : 0; o.y = x.y ? 1 : 0; o.z = x.z ? 1 : 0; o.w = x.w ? 1 : 0;
    } else if (fmt == 1) { // fp32 0.0/1.0
        float4 x = ((const float4*)mraw)[i];
        o.x = (x.x != 0.f) ? 1 : 0; o.y = (x.y != 0.f) ? 1 : 0;
        o.z = (x.z != 0.f) ? 1 : 0; o.w = (x.w != 0.f) ? 1 : 0;
    } else {               // bool bytes
        uchar4 x = ((const uchar4*)mraw)[i];
        o.x = x.x ? 1 : 0; o.y = x.y ? 1 : 0; o.z = x.z ? 1 : 0; o.w = x.w ? 1 : 0;
    }
    ((uchar4*)Mb)[i] = o;
}

// ---- prep: V -> V^T bf16 (64x64 tiles through LDS) -----------------------
__global__ void prep_vt(const float* __restrict__ v, unsigned short* __restrict__ Vt)
{
    __shared__ unsigned short sT[64 * 72];
    const int bh = blockIdx.x >> 4;
    const int st = blockIdx.x & 15;
    const int t = threadIdx.x;
    const float* vb = v + (size_t)(bh * S_LEN + st * 64) * D_DIM;
#pragma unroll
    for (int p = 0; p < 4; ++p) {
        int lin = p * 256 + t;
        int r = lin >> 4;
        int c = lin & 15;
        f32x4 x = ((const f32x4*)(vb + r * D_DIM))[c];
        unsigned short* dst = &sT[r * 72 + c * 4];
#pragma unroll
        for (int j = 0; j < 4; ++j) dst[j] = f2bf(x[j]);
    }
    __syncthreads();
    unsigned short* ob = Vt + (size_t)bh * D_DIM * S_LEN + st * 64;
#pragma unroll
    for (int p = 0; p < 4; ++p) {
        int lin = p * 256 + t;
        int d = lin >> 4;
        int s4 = (lin & 15) * 4;
        u16x4 o;
#pragma unroll
        for (int j = 0; j < 4; ++j) o[j] = sT[(s4 + j) * 72 + d];
        *(u16x4*)&ob[d * S_LEN + s4] = o;
    }
}

// ---- main: scores -> softmax -> attn write + PV --------------------------
// 1 wg (4 waves) per (bh, 16-row q tile). MFMA B fragments (and the Q A
// fragment) are 16B-contiguous rows of Kb / Vt -> loaded DIRECTLY from
// global (L2-resident: 256 KB/bh shared by 64 blocks). No K/V LDS staging,
// no per-tile barriers: 2 barriers total instead of 32. LDS holds only the
// 16x1024 score row-block (bf16, padded stride).
__global__ __launch_bounds__(256, 4)
void attn_main(const float* __restrict__ simg_, const unsigned short* __restrict__ Qb,
               const unsigned short* __restrict__ Kb, const unsigned short* __restrict__ Vtb,
               const unsigned char* __restrict__ Mb, float* __restrict__ out,
               float* __restrict__ attn)
{
    __shared__ __align__(16) unsigned short sS[QT * SSTR];

    const int blk = blockIdx.x;
    const int bh = blk >> 6;
    const int qt = blk & 63;
    const int b = bh >> 4;
    const int t = threadIdx.x;
    const int w = t >> 6;
    const int lane = t & 63;
    const int quad = lane >> 4;
    const int l15 = lane & 15;

    const unsigned short* Qg = Qb + (size_t)(bh * S_LEN + qt * QT) * D_DIM;
    const unsigned short* Kg = Kb + (size_t)bh * S_LEN * D_DIM;
    const unsigned short* Vg = Vtb + (size_t)bh * D_DIM * S_LEN;
    const float* simg = simg_ + ((size_t)(bh * S_LEN + qt * QT)) * S_LEN;
    const unsigned char* mg = Mb + ((size_t)(b * S_LEN + qt * QT)) * S_LEN;
    float* attng = attn + ((size_t)(bh * S_LEN + qt * QT)) * S_LEN;

    // ---- phase 1: raw scores = (q/8)@k^T, park bf16 in LDS. No barriers.
    const int n0 = w * 16;
    const bf16x8 av0 = *(const bf16x8*)&Qg[l15 * D_DIM + quad * 8];
    const bf16x8 av1 = *(const bf16x8*)&Qg[l15 * D_DIM + 32 + quad * 8];
#pragma unroll 4
    for (int kt = 0; kt < 16; ++kt) {
        const unsigned short* kp = &Kg[(size_t)(kt * 64 + n0 + l15) * D_DIM + quad * 8];
        bf16x8 bv0 = *(const bf16x8*)kp;
        bf16x8 bv1 = *(const bf16x8*)(kp + 32);
        f32x4 acc = {0.f, 0.f, 0.f, 0.f};
        acc = __builtin_amdgcn_mfma_f32_16x16x32_bf16(av0, bv0, acc, 0, 0, 0);
        acc = __builtin_amdgcn_mfma_f32_16x16x32_bf16(av1, bv1, acc, 0, 0, 0);
        const int colg = kt * 64 + n0 + l15;
#pragma unroll
        for (int r = 0; r < 4; ++r)
            sS[(quad * 4 + r) * SSTR + colg] = f2bf(acc[r]);
    }
    __syncthreads();

    // ---- phase 2: mask + similarity (coalesced f32x4) + exact softmax.
    //      Wave w owns rows 4w..4w+3. Write attn fp32, rewrite probs bf16.
#pragma unroll 1
    for (int rr = 0; rr < 4; ++rr) {
        const int row = w * 4 + rr;
        const float* sp = simg + (size_t)row * S_LEN;
        const unsigned char* mp = mg + (size_t)row * S_LEN;
        float vals[16];
        float mx = -3.0e38f;
#pragma unroll
        for (int j = 0; j < 4; ++j) {
            int col = j * 256 + lane * 4;
            u16x4 x = *(const u16x4*)&sS[row * SSTR + col];
            f32x4 sv = *(const f32x4*)&sp[col];
            uchar4 mk = *(const uchar4*)&mp[col];
            float f0 = mk.x ? NEG_FILL : (bf2f(x[0]) + sv[0]);
            float f1 = mk.y ? NEG_FILL : (bf2f(x[1]) + sv[1]);
            float f2 = mk.z ? NEG_FILL : (bf2f(x[2]) + sv[2]);
            float f3 = mk.w ? NEG_FILL : (bf2f(x[3]) + sv[3]);
            vals[j * 4 + 0] = f0; vals[j * 4 + 1] = f1;
            vals[j * 4 + 2] = f2; vals[j * 4 + 3] = f3;
            mx = fmaxf(mx, fmaxf(fmaxf(f0, f1), fmaxf(f2, f3)));
        }
#pragma unroll
        for (int off = 32; off > 0; off >>= 1)
            mx = fmaxf(mx, __shfl_xor(mx, off, 64));
        float sum = 0.f;
#pragma unroll
        for (int i = 0; i < 16; ++i) {
            float e = exp2f((vals[i] - mx) * LOG2E);
            vals[i] = e;
            sum += e;
        }
#pragma unroll
        for (int off = 32; off > 0; off >>= 1)
            sum += __shfl_xor(sum, off, 64);
        const float rinv = 1.0f / sum;
#pragma unroll
        for (int j = 0; j < 4; ++j) {
            int col = j * 256 + lane * 4;
            f32x4 p;
            u16x4 pb;
#pragma unroll
            for (int i = 0; i < 4; ++i) {
                float pi = vals[j * 4 + i] * rinv;
                p[i] = pi;
                pb[i] = f2bf(pi);
            }
            *(f32x4*)&attng[(size_t)row * S_LEN + col] = p;   // 1 KB/wave coalesced
            *(u16x4*)&sS[row * SSTR + col] = pb;
        }
    }
    __syncthreads();

    // ---- phase 3: out = P @ V. A from LDS probs, B direct from Vt global.
    f32x4 oacc = {0.f, 0.f, 0.f, 0.f};
    const int d0 = w * 16;
#pragma unroll 4
    for (int kt = 0; kt < 16; ++kt) {
        const unsigned short* vp = &Vg[(size_t)(d0 + l15) * S_LEN + kt * 64 + quad * 8];
        bf16x8 bv0 = *(const bf16x8*)vp;
        bf16x8 bv1 = *(const bf16x8*)(vp + 32);
        bf16x8 pa0 = *(const bf16x8*)&sS[l15 * SSTR + kt * 64 + quad * 8];
        bf16x8 pa1 = *(const bf16x8*)&sS[l15 * SSTR + kt * 64 + 32 + quad * 8];
        oacc = __builtin_amdgcn_mfma_f32_16x16x32_bf16(pa0, bv0, oacc, 0, 0, 0);
        oacc = __builtin_amdgcn_mfma_f32_16x16x32_bf16(pa1, bv1, oacc, 0, 0, 0);
    }
    float* og = out + ((size_t)(bh * S_LEN + qt * QT)) * D_DIM;
#pragma unroll
    for (int r = 0; r < 4; ++r) {
        int row = quad * 4 + r;
        og[row * D_DIM + d0 + l15] = oacc[r];
    }
}

extern "C" void kernel_launch(void* const* d_in, const int* in_sizes, int n_in,
                              void* d_out, int out_size, void* d_ws, size_t ws_size,
                              hipStream_t stream)
{
    const float* q = (const float*)d_in[0];
    const float* k = (const float*)d_in[1];
    const float* v = (const float*)d_in[2];
    const float* sim = (const float*)d_in[3];
    const void* mask = d_in[4];
    float* out = (float*)d_out;
    float* attn = out + (size_t)4 * 16 * 1024 * 64;   // output first, then attn

    char* ws = (char*)d_ws;                           // needs 28 MB
    unsigned short* Qb = (unsigned short*)(ws + (size_t)0);
    unsigned short* Kb = (unsigned short*)(ws + ((size_t)8 << 20));
    unsigned short* Vt = (unsigned short*)(ws + ((size_t)16 << 20));
    unsigned char*  Mb = (unsigned char*)(ws + ((size_t)24 << 20));

    prep_qkm<<<4096, 256, 0, stream>>>(q, k, mask, Qb, Kb, Mb);
    prep_vt<<<1024, 256, 0, stream>>>(v, Vt);
    attn_main<<<4096, 256, 0, stream>>>(sim, Qb, Kb, Vt, Mb, out, attn);
}